// Round 19
// baseline (154.743 us; speedup 1.0000x reference)
//
#include <hip/hip_runtime.h>
#include <hip/hip_bf16.h>
#include <stdint.h>
#include <stddef.h>

#define DIM 1024
#define SEQ 2048
#define KF 24

using f32x4    = __attribute__((ext_vector_type(4))) float;
using bf16x8   = __attribute__((ext_vector_type(8))) short;
using uint32x4 = __attribute__((ext_vector_type(4))) unsigned int;

__device__ __forceinline__ unsigned short f2bf(float f){
  union { float f; unsigned int i; } v; v.f = f;
  unsigned int r = v.i + 0x7FFFu + ((v.i >> 16) & 1u);  // RNE
  return (unsigned short)(r >> 16);
}
// D = a.bf16[0]*b.bf16[0] + a.bf16[1]*b.bf16[1] + c   (V_DOT2_F32_BF16, VOP3P)
__device__ __forceinline__ float dot2bf(unsigned int a, unsigned int b, float c){
  float d;
  asm("v_dot2_f32_bf16 %0, %1, %2, %3" : "=v"(d) : "v"(a), "v"(b), "v"(c));
  return d;
}
__device__ __forceinline__ unsigned vext(const uint32x4 v, int i){
  return i == 0 ? v.x : i == 1 ? v.y : i == 2 ? v.z : v.w;
}
__device__ __forceinline__ void gload_lds16(const void* g, void* l){
  __builtin_amdgcn_global_load_lds(
      (const __attribute__((address_space(1))) unsigned int*)g,
      (__attribute__((address_space(3))) unsigned int*)l, 16, 0, 0);
}
__device__ __forceinline__ uint32x4 make_srsrc(const void* base, unsigned bytes){
  uint32x4 r;
  r.x = (unsigned)(uintptr_t)base;
  r.y = (unsigned)((uintptr_t)base >> 32);   // stride=0
  r.z = bytes;                               // num_records (bytes); OOB loads -> 0
  r.w = 0x00020000u;                         // raw untyped dword
  return r;
}

// ---------------- prep: x fp32 -> bf16 ----------------
__global__ void k_cvt_x(const float* __restrict__ x, unsigned short* __restrict__ xb){
  int i = blockIdx.x * 256 + threadIdx.x;            // each thread 4 elems
  const float4* x4 = (const float4*)x;
  float4 v = x4[i];
  ushort4 o;
  o.x = f2bf(v.x); o.y = f2bf(v.y); o.z = f2bf(v.z); o.w = f2bf(v.w);
  *(ushort4*)(xb + (size_t)i * 4) = o;
}

// ---------------- prep: M_inputs transpose -> bf16 (B^T, [d][e]) ----------------
__global__ void k_tr_M(const float* __restrict__ Mi, unsigned short* __restrict__ MbT){
  __shared__ float tile[32][33];
  int e0 = blockIdx.y * 32, d0 = blockIdx.x * 32;
  int tx = threadIdx.x, ty = threadIdx.y;            // block (32,8)
  #pragma unroll
  for (int r = 0; r < 32; r += 8)
    tile[ty + r][tx] = Mi[(size_t)(e0 + ty + r) * DIM + d0 + tx];
  __syncthreads();
  #pragma unroll
  for (int r = 0; r < 32; r += 8)
    MbT[(size_t)(d0 + ty + r) * DIM + e0 + tx] = f2bf(tile[tx][ty + r]);
}

// ---------------- prep: pe packed pairs, CHUNK-INTERLEAVED [k][d][8] ----------------
// pepk2[k][d][i] holds pair (pe[2*r2], pe[2*r2+1]) for r2 = 8k+i.  A lane's
// per-chunk 8 pairs are 32B contiguous -> pe loads wave-coalesced (2KB/wave).
__global__ void k_pe(const float* __restrict__ filters, const float* __restrict__ Mf,
                     unsigned int* __restrict__ pepk2){
  int r2 = blockIdx.x * 256 + threadIdx.x;           // 0..511 (grid.x = 2)
  int d  = blockIdx.y;                               // 0..1023
  float a0 = 0.f, a1 = 0.f;
  #pragma unroll
  for (int k = 0; k < KF; ++k){
    float mf = Mf[(size_t)k * DIM + d];              // uniform per block
    a0 += filters[(size_t)(4 * r2)     * KF + k] * mf;
    a1 += filters[(size_t)(4 * r2 + 2) * KF + k] * mf;
  }
  unsigned int lo = f2bf(2.f * a0), hi = f2bf(2.f * a1);
  pepk2[(size_t)(r2 >> 3) * 8192 + (size_t)d * 8 + (r2 & 7)] = lo | (hi << 16);
}

// ---------------- GEMM: x_proj = x @ M_inputs, epilogue writes Bg4 ----------------
// Bg4 elem (b,p,j,d) at u32 index (b*2+p)*1048576 + (j>>2)*4096 + d*4 + (j&3),
// value = y_j | y_{j-1}<<16 (in-stream; y_{-1}=0).  Lane's 4 consecutive j are
// 16B contiguous -> conv loads dwordx4.
#define BM 128
#define BN 128
#define BKK 64
__global__ void k_gemm(const unsigned short* __restrict__ A,
                       const unsigned short* __restrict__ Bt,
                       unsigned int* __restrict__ Bg){
  __shared__ unsigned short As[BM * BKK];   // 16 KB, XOR-swizzled (unit16B ^= row&7)
  __shared__ unsigned short Bs[BN * BKK];   // 16 KB
  int tid  = threadIdx.x;
  int lane = tid & 63, wave = tid >> 6;
  int wm = wave >> 1, wn = wave & 1;
  int trow0 = blockIdx.x * BM;
  int ncol0 = blockIdx.y * BN;

  f32x4 acc[4][4] = {};

  for (int kt = 0; kt < 1024 / BKK; ++kt){
    __syncthreads();
    #pragma unroll
    for (int g = 0; g < 4; ++g){
      int c  = wave * 4 + g;              // chunk 0..15, 1KB each
      int mr = c * 8 + (lane >> 3);       // tile row this lane stages
      int u  = lane & 7;                  // physical 16B unit within row
      int su = u ^ (mr & 7);              // source (logical) unit
      const unsigned short* srcA = A + (size_t)(trow0 + mr) * 1024 + kt * BKK + su * 8;
      gload_lds16(srcA, (char*)As + c * 1024);
      const unsigned short* srcB = Bt + (size_t)(ncol0 + mr) * 1024 + kt * BKK + su * 8;
      gload_lds16(srcB, (char*)Bs + c * 1024);
    }
    __syncthreads();

    bf16x8 af[4][2], bfr[4][2];
    #pragma unroll
    for (int mi = 0; mi < 4; ++mi){
      int row = wm * 64 + mi * 16 + (lane & 15);
      #pragma unroll
      for (int ks = 0; ks < 2; ++ks){
        int u = ((lane >> 4) + 4 * ks) ^ (row & 7);
        af[mi][ks] = *(const bf16x8*)((const char*)As + row * 128 + u * 16);
      }
    }
    #pragma unroll
    for (int ni = 0; ni < 4; ++ni){
      int row = wn * 64 + ni * 16 + (lane & 15);
      #pragma unroll
      for (int ks = 0; ks < 2; ++ks){
        int u = ((lane >> 4) + 4 * ks) ^ (row & 7);
        bfr[ni][ks] = *(const bf16x8*)((const char*)Bs + row * 128 + u * 16);
      }
    }
    #pragma unroll
    for (int mi = 0; mi < 4; ++mi)
      #pragma unroll
      for (int ni = 0; ni < 4; ++ni)
        #pragma unroll
        for (int ks = 0; ks < 2; ++ks)
          acc[mi][ni] = __builtin_amdgcn_mfma_f32_16x16x32_bf16(
              af[mi][ks], bfr[ni][ks], acc[mi][ni], 0, 0, 0);
  }

  unsigned short* Bh = (unsigned short*)Bg;
  #pragma unroll
  for (int mi = 0; mi < 4; ++mi)
    #pragma unroll
    for (int ni = 0; ni < 4; ++ni){
      int col = ncol0 + wn * 64 + ni * 16 + (lane & 15);
      #pragma unroll
      for (int reg = 0; reg < 4; ++reg){
        int row = trow0 + wm * 64 + mi * 16 + (lane >> 4) * 4 + reg;
        unsigned short y = f2bf(acc[mi][ni][reg]);
        int t = row & 2047, bq = row >> 11;
        int p = t & 1, j = t >> 1;
        size_t strm = ((size_t)bq * 2 + p) * 1048576;
        size_t e_lo = strm + (size_t)(j >> 2) * 4096 + (size_t)col * 4 + (j & 3);
        if (j == 0) Bg[e_lo] = (unsigned int)y;        // lo=y, hi=y_{-1}=0
        else        Bh[2 * e_lo] = y;                  // lo half
        if (j < 1023){
          int j1 = j + 1;
          size_t e_hi = strm + (size_t)(j1 >> 2) * 4096 + (size_t)col * 4 + (j1 & 3);
          Bh[2 * e_hi + 1] = y;                        // hi half of entry j+1
        }
      }
    }
}

// ---------------- depthwise causal conv: FUSED TILE-PAIR, shared x-window ----------
// Block computes tiles mt and mt+1 (mt even) over ONE x-window sweep: for pe
// chunks shifted by +2, both tiles share the identical j<->idx mapping
// (j = idx+16c-32-{0,1}), so each 4-x-quad load feeds 512 dot2 (2x the R18
// ratio) -> per-chunk compute (2048cy) > stall (~1500cy) even in wave-lockstep.
// Tile A's last-2-chunk pe reads wrap OOB -> 0 -> harmless no-op dot2s (no
// branches).  x-read traffic halves.  3-buffer rotation + vmcnt(0) unchanged
// from passing R18.
#define BLX4(dst, so) \
  asm volatile("buffer_load_dwordx4 %0, %1, %2, %3 offen" \
               : "=v"(dst) : "v"(voff), "s"(xrsrc), "s"(so))
#define BLP4_0(dst, so) \
  asm volatile("buffer_load_dwordx4 %0, %1, %2, %3 offen" \
               : "=v"(dst) : "v"(pvoff), "s"(prsrc), "s"(so))
#define BLP4_16(dst, so) \
  asm volatile("buffer_load_dwordx4 %0, %1, %2, %3 offen offset:16" \
               : "=v"(dst) : "v"(pvoff), "s"(prsrc), "s"(so))

__device__ __forceinline__ void phase_old(const uint32x4* XBO, const uint32x4* pv,
                                          float* acc){
  #pragma unroll
  for (int q = 0; q < 8; ++q)
    #pragma unroll
    for (int m = 0; m < 32; ++m){
      int idx = m - 2 * q + 16;
      if (idx >= 2 && idx < 16)
        acc[m] = dot2bf(vext(pv[q >> 2], q & 3), vext(XBO[(idx >> 2) & 3], idx & 3),
                        acc[m]);
    }
}
__device__ __forceinline__ void phase_mid_new(const uint32x4* XBM, const uint32x4* XBN,
                                              const uint32x4* pv, float* acc){
  #pragma unroll
  for (int q = 0; q < 8; ++q)
    #pragma unroll
    for (int m = 0; m < 32; ++m){
      int idx = m - 2 * q + 16;
      if (idx >= 16){
        unsigned w = (idx < 32) ? vext(XBM[(idx >> 2) & 3], idx & 3)
                                : vext(XBN[(idx >> 2) & 3], idx & 3);
        acc[m] = dot2bf(vext(pv[q >> 2], q & 3), w, acc[m]);
      }
    }
}

#define BODY2(XBO_, XBM_, XBN_, C) do{                                           \
  phase_old(XBO_, pvA, accA);                                                    \
  phase_old(XBO_, pvB, accB);                                                    \
  __builtin_amdgcn_sched_barrier(0);                                             \
  { unsigned _xs = (unsigned)(4 * (C) + 4) * 16384u;                             \
    BLX4(XBO_[0], _xs);                                                          \
    BLX4(XBO_[1], _xs + 16384u);                                                 \
    BLX4(XBO_[2], _xs + 32768u);                                                 \
    BLX4(XBO_[3], _xs + 49152u);                                                 \
    unsigned _psA = pbaseA - 32768u * (unsigned)((C) + 1);                       \
    unsigned _psB = pbaseB - 32768u * (unsigned)((C) + 1);                       \
    BLP4_0(npvA[0], _psA); BLP4_16(npvA[1], _psA);                               \
    BLP4_0(npvB[0], _psB); BLP4_16(npvB[1], _psB); }                             \
  __builtin_amdgcn_sched_barrier(0);                                             \
  phase_mid_new(XBM_, XBN_, pvA, accA);                                          \
  phase_mid_new(XBM_, XBN_, pvB, accB);                                          \
  asm volatile("s_waitcnt vmcnt(0)" ::: "memory");                               \
  __builtin_amdgcn_sched_barrier(0);                                             \
  pvA[0] = npvA[0]; pvA[1] = npvA[1];                                            \
  pvB[0] = npvB[0]; pvB[1] = npvB[1];                                            \
}while(0)

__global__ __launch_bounds__(256, 3)
void k_conv(const unsigned int* __restrict__ Bg,     // Bg4 interleaved (see k_gemm)
            const unsigned int* __restrict__ pepk2,  // [64][1024][8] pe pairs
            float* __restrict__ out){                // [4][2048][1024] f32
  int tid  = threadIdx.x;
  int bid  = blockIdx.x;                    // 0..511
  int bp   = bid & 7;                       // XCD pin: stream -> one XCD
  int rest = bid >> 3;                      // 0..63
  int dblk = rest & 3;
  int pk   = 15 - (rest >> 2);              // LPT: longest pairs dispatch first
  int mt   = 2 * pk;                        // tiles (mt, mt+1), m0 = 32mt
  int b = bp >> 1, p = bp & 1;
  int d = dblk * 256 + tid;                 // 0..1023

  uint32x4 xrsrc = make_srsrc(Bg + (size_t)bp * 1048576, 4194304u);  // 4MB stream
  uint32x4 prsrc = make_srsrc(pepk2, 2097152u);

  unsigned voff  = (unsigned)(d * 16);      // lane's 16B within a quad row
  unsigned pvoff = (unsigned)(d * 32);      // lane's 32B pe record within a chunk

  uint32x4 B0[4], B1[4], B2[4];
  uint32x4 pvA[2], npvA[2], pvB[2], npvB[2];
  float accA[32], accB[32];

  unsigned pbaseA = (2u * (unsigned)mt + 1u) * 32768u;  // tile A pe chunk 0
  unsigned pbaseB = (2u * (unsigned)mt + 3u) * 32768u;  // tile B pe chunk 0
  int nch = 2 * mt + 4;                     // tile B's chunk count

  #pragma unroll
  for (int m = 0; m < 32; ++m){ accA[m] = 0.f; accB[m] = 0.f; }

  // prologue: chunk-0 window quads -8..3 (negatives OOB -> 0) + both pe streams
  #pragma unroll
  for (int k = 0; k < 4; ++k) BLX4(B0[k], (unsigned)(k - 8) * 16384u);
  #pragma unroll
  for (int k = 0; k < 4; ++k) BLX4(B1[k], (unsigned)(k - 4) * 16384u);
  #pragma unroll
  for (int k = 0; k < 4; ++k) BLX4(B2[k], (unsigned)k * 16384u);
  BLP4_0(pvA[0], pbaseA); BLP4_16(pvA[1], pbaseA);
  BLP4_0(pvB[0], pbaseB); BLP4_16(pvB[1], pbaseB);
  asm volatile("s_waitcnt vmcnt(0)" ::: "memory");
  __builtin_amdgcn_sched_barrier(0);

  int c = 0;
  for (;;){
    BODY2(B0, B1, B2, c); if (++c == nch) break;
    BODY2(B1, B2, B0, c); if (++c == nch) break;
    BODY2(B2, B0, B1, c); if (++c == nch) break;
  }

  float* ocA = out + ((size_t)(b * SEQ + p) * 1024 + d) + (size_t)mt * 32 * 2048;
  float* ocB = ocA + (size_t)32 * 2048;
  #pragma unroll
  for (int m = 0; m < 32; ++m) ocA[(size_t)m * 2048] = accA[m];
  #pragma unroll
  for (int m = 0; m < 32; ++m) ocB[(size_t)m * 2048] = accB[m];
}

extern "C" void kernel_launch(void* const* d_in, const int* in_sizes, int n_in,
                              void* d_out, int out_size, void* d_ws, size_t ws_size,
                              hipStream_t stream){
  const float* x       = (const float*)d_in[0];
  const float* filters = (const float*)d_in[1];
  const float* Mi      = (const float*)d_in[2];
  const float* Mf      = (const float*)d_in[3];

  char* ws = (char*)d_ws;
  unsigned short* Xb    = (unsigned short*)(ws);                              // 16 MB
  unsigned int*   Bg    = (unsigned int*)  (ws + (size_t)16 * 1024 * 1024);   // 32 MB
  unsigned short* MbT   = (unsigned short*)(ws + (size_t)48 * 1024 * 1024);   //  2 MB
  unsigned int*   pepk2 = (unsigned int*)  (ws + (size_t)50 * 1024 * 1024);   //  2 MB
  float* out = (float*)d_out;

  hipLaunchKernelGGL(k_cvt_x, dim3(8192), dim3(256), 0, stream, x, Xb);
  hipLaunchKernelGGL(k_tr_M,  dim3(32, 32), dim3(32, 8), 0, stream, Mi, MbT);
  hipLaunchKernelGGL(k_pe,    dim3(2, 1024), dim3(256), 0, stream, filters, Mf, pepk2);
  hipLaunchKernelGGL(k_gemm,  dim3(64, 8), dim3(256), 0, stream, Xb, MbT, Bg);
  hipLaunchKernelGGL(k_conv,  dim3(512), dim3(256), 0, stream, Bg, pepk2, out);
}

// Round 22
// 127.910 us; speedup vs baseline: 1.2098x; 1.2098x over previous
//
#include <hip/hip_runtime.h>
#include <hip/hip_bf16.h>
#include <stdint.h>
#include <stddef.h>

#define DIM 1024
#define SEQ 2048
#define KF 24

using f32x4    = __attribute__((ext_vector_type(4))) float;
using bf16x8   = __attribute__((ext_vector_type(8))) short;
using uint32x4 = __attribute__((ext_vector_type(4))) unsigned int;

__device__ __forceinline__ unsigned short f2bf(float f){
  union { float f; unsigned int i; } v; v.f = f;
  unsigned int r = v.i + 0x7FFFu + ((v.i >> 16) & 1u);  // RNE
  return (unsigned short)(r >> 16);
}
// D = a.bf16[0]*b.bf16[0] + a.bf16[1]*b.bf16[1] + c   (V_DOT2_F32_BF16, VOP3P)
__device__ __forceinline__ float dot2bf(unsigned int a, unsigned int b, float c){
  float d;
  asm("v_dot2_f32_bf16 %0, %1, %2, %3" : "=v"(d) : "v"(a), "v"(b), "v"(c));
  return d;
}
__device__ __forceinline__ unsigned vext(const uint32x4 v, int i){
  return i == 0 ? v.x : i == 1 ? v.y : i == 2 ? v.z : v.w;
}
__device__ __forceinline__ void gload_lds16(const void* g, void* l){
  __builtin_amdgcn_global_load_lds(
      (const __attribute__((address_space(1))) unsigned int*)g,
      (__attribute__((address_space(3))) unsigned int*)l, 16, 0, 0);
}
__device__ __forceinline__ uint32x4 make_srsrc(const void* base, unsigned bytes){
  uint32x4 r;
  r.x = (unsigned)(uintptr_t)base;
  r.y = (unsigned)((uintptr_t)base >> 32);   // stride=0
  r.z = bytes;                               // num_records (bytes); OOB loads -> 0
  r.w = 0x00020000u;                         // raw untyped dword
  return r;
}

// ---------------- prep: x fp32 -> bf16 ----------------
__global__ void k_cvt_x(const float* __restrict__ x, unsigned short* __restrict__ xb){
  int i = blockIdx.x * 256 + threadIdx.x;            // each thread 4 elems
  const float4* x4 = (const float4*)x;
  float4 v = x4[i];
  ushort4 o;
  o.x = f2bf(v.x); o.y = f2bf(v.y); o.z = f2bf(v.z); o.w = f2bf(v.w);
  *(ushort4*)(xb + (size_t)i * 4) = o;
}

// ---------------- prep: M_inputs transpose -> bf16 (B^T, [d][e]) ----------------
__global__ void k_tr_M(const float* __restrict__ Mi, unsigned short* __restrict__ MbT){
  __shared__ float tile[32][33];
  int e0 = blockIdx.y * 32, d0 = blockIdx.x * 32;
  int tx = threadIdx.x, ty = threadIdx.y;            // block (32,8)
  #pragma unroll
  for (int r = 0; r < 32; r += 8)
    tile[ty + r][tx] = Mi[(size_t)(e0 + ty + r) * DIM + d0 + tx];
  __syncthreads();
  #pragma unroll
  for (int r = 0; r < 32; r += 8)
    MbT[(size_t)(d0 + ty + r) * DIM + e0 + tx] = f2bf(tile[tx][ty + r]);
}

// ---------------- prep: pe packed pairs, CHUNK-INTERLEAVED [k][d][8] ----------------
// pepk2[k][d][i] holds pair (pe[2*r2], pe[2*r2+1]) for r2 = 8k+i.  A lane's
// per-chunk 8 pairs are 32B contiguous -> pe loads wave-coalesced (2KB/wave).
__global__ void k_pe(const float* __restrict__ filters, const float* __restrict__ Mf,
                     unsigned int* __restrict__ pepk2){
  int r2 = blockIdx.x * 256 + threadIdx.x;           // 0..511 (grid.x = 2)
  int d  = blockIdx.y;                               // 0..1023
  float a0 = 0.f, a1 = 0.f;
  #pragma unroll
  for (int k = 0; k < KF; ++k){
    float mf = Mf[(size_t)k * DIM + d];              // uniform per block
    a0 += filters[(size_t)(4 * r2)     * KF + k] * mf;
    a1 += filters[(size_t)(4 * r2 + 2) * KF + k] * mf;
  }
  unsigned int lo = f2bf(2.f * a0), hi = f2bf(2.f * a1);
  pepk2[(size_t)(r2 >> 3) * 8192 + (size_t)d * 8 + (r2 & 7)] = lo | (hi << 16);
}

// ---------------- GEMM: x_proj = x @ M_inputs, epilogue writes Bg4 ----------------
// Bg4 elem (b,p,j,d) at u32 index (b*2+p)*1048576 + (j>>2)*4096 + d*4 + (j&3),
// value = y_j | y_{j-1}<<16 (in-stream; y_{-1}=0).  Lane's 4 consecutive j are
// 16B contiguous -> conv loads dwordx4.
#define BM 128
#define BN 128
#define BKK 64
__global__ void k_gemm(const unsigned short* __restrict__ A,
                       const unsigned short* __restrict__ Bt,
                       unsigned int* __restrict__ Bg){
  __shared__ unsigned short As[BM * BKK];   // 16 KB, XOR-swizzled (unit16B ^= row&7)
  __shared__ unsigned short Bs[BN * BKK];   // 16 KB
  int tid  = threadIdx.x;
  int lane = tid & 63, wave = tid >> 6;
  int wm = wave >> 1, wn = wave & 1;
  int trow0 = blockIdx.x * BM;
  int ncol0 = blockIdx.y * BN;

  f32x4 acc[4][4] = {};

  for (int kt = 0; kt < 1024 / BKK; ++kt){
    __syncthreads();
    #pragma unroll
    for (int g = 0; g < 4; ++g){
      int c  = wave * 4 + g;              // chunk 0..15, 1KB each
      int mr = c * 8 + (lane >> 3);       // tile row this lane stages
      int u  = lane & 7;                  // physical 16B unit within row
      int su = u ^ (mr & 7);              // source (logical) unit
      const unsigned short* srcA = A + (size_t)(trow0 + mr) * 1024 + kt * BKK + su * 8;
      gload_lds16(srcA, (char*)As + c * 1024);
      const unsigned short* srcB = Bt + (size_t)(ncol0 + mr) * 1024 + kt * BKK + su * 8;
      gload_lds16(srcB, (char*)Bs + c * 1024);
    }
    __syncthreads();

    bf16x8 af[4][2], bfr[4][2];
    #pragma unroll
    for (int mi = 0; mi < 4; ++mi){
      int row = wm * 64 + mi * 16 + (lane & 15);
      #pragma unroll
      for (int ks = 0; ks < 2; ++ks){
        int u = ((lane >> 4) + 4 * ks) ^ (row & 7);
        af[mi][ks] = *(const bf16x8*)((const char*)As + row * 128 + u * 16);
      }
    }
    #pragma unroll
    for (int ni = 0; ni < 4; ++ni){
      int row = wn * 64 + ni * 16 + (lane & 15);
      #pragma unroll
      for (int ks = 0; ks < 2; ++ks){
        int u = ((lane >> 4) + 4 * ks) ^ (row & 7);
        bfr[ni][ks] = *(const bf16x8*)((const char*)Bs + row * 128 + u * 16);
      }
    }
    #pragma unroll
    for (int mi = 0; mi < 4; ++mi)
      #pragma unroll
      for (int ni = 0; ni < 4; ++ni)
        #pragma unroll
        for (int ks = 0; ks < 2; ++ks)
          acc[mi][ni] = __builtin_amdgcn_mfma_f32_16x16x32_bf16(
              af[mi][ks], bfr[ni][ks], acc[mi][ni], 0, 0, 0);
  }

  unsigned short* Bh = (unsigned short*)Bg;
  #pragma unroll
  for (int mi = 0; mi < 4; ++mi)
    #pragma unroll
    for (int ni = 0; ni < 4; ++ni){
      int col = ncol0 + wn * 64 + ni * 16 + (lane & 15);
      #pragma unroll
      for (int reg = 0; reg < 4; ++reg){
        int row = trow0 + wm * 64 + mi * 16 + (lane >> 4) * 4 + reg;
        unsigned short y = f2bf(acc[mi][ni][reg]);
        int t = row & 2047, bq = row >> 11;
        int p = t & 1, j = t >> 1;
        size_t strm = ((size_t)bq * 2 + p) * 1048576;
        size_t e_lo = strm + (size_t)(j >> 2) * 4096 + (size_t)col * 4 + (j & 3);
        if (j == 0) Bg[e_lo] = (unsigned int)y;        // lo=y, hi=y_{-1}=0
        else        Bh[2 * e_lo] = y;                  // lo half
        if (j < 1023){
          int j1 = j + 1;
          size_t e_hi = strm + (size_t)(j1 >> 2) * 4096 + (size_t)col * 4 + (j1 & 3);
          Bh[2 * e_hi + 1] = y;                        // hi half of entry j+1
        }
      }
    }
}

// ---------------- depthwise causal conv: R18 passing body + NON-TEMPORAL stores ----
// out[m0+m] = sum_{r<=m0+m} pe[r]*y[m0+m-r], m in [0,32), one tile per block.
// Body identical to passing R18 (90.5us): phase_old (56 dot2) -> prefetch 4
// x-quads + 2 pe dwordx4 (soffset-dynamic, the PROVEN OOB-zero path) ->
// phase_mid_new (200 dot2) -> vmcnt(0).  ONE change: output stores are
// __builtin_nontemporal_store (bypass L2).  Theory: the 32MB output write
// stream was flushing the 4MB XCD-pinned Bg stream out of L2 (FETCH 40MB =
// full HBM re-fetch; stall/chunk ~1300cy = HBM class).  nt-stores keep Bg
// L2-resident -> x loads become ~300cy L2 hits, hidden under the 800cy
// phase_mid_new -> stall collapses.  Decisive counter: FETCH_SIZE 40 -> <25MB.
#define BLX4(dst, so) \
  asm volatile("buffer_load_dwordx4 %0, %1, %2, %3 offen" \
               : "=v"(dst) : "v"(voff), "s"(xrsrc), "s"(so))
#define BLP4_0(dst, so) \
  asm volatile("buffer_load_dwordx4 %0, %1, %2, %3 offen" \
               : "=v"(dst) : "v"(pvoff), "s"(prsrc), "s"(so))
#define BLP4_16(dst, so) \
  asm volatile("buffer_load_dwordx4 %0, %1, %2, %3 offen offset:16" \
               : "=v"(dst) : "v"(pvoff), "s"(prsrc), "s"(so))

__device__ __forceinline__ void phase_old(const uint32x4* XBO, const uint32x4* pv,
                                          float* acc){
  #pragma unroll
  for (int q = 0; q < 8; ++q)
    #pragma unroll
    for (int m = 0; m < 32; ++m){
      int idx = m - 2 * q + 16;
      if (idx >= 2 && idx < 16)
        acc[m] = dot2bf(vext(pv[q >> 2], q & 3), vext(XBO[(idx >> 2) & 3], idx & 3),
                        acc[m]);
    }
}
__device__ __forceinline__ void phase_mid_new(const uint32x4* XBM, const uint32x4* XBN,
                                              const uint32x4* pv, float* acc){
  #pragma unroll
  for (int q = 0; q < 8; ++q)
    #pragma unroll
    for (int m = 0; m < 32; ++m){
      int idx = m - 2 * q + 16;
      if (idx >= 16){
        unsigned w = (idx < 32) ? vext(XBM[(idx >> 2) & 3], idx & 3)
                                : vext(XBN[(idx >> 2) & 3], idx & 3);
        acc[m] = dot2bf(vext(pv[q >> 2], q & 3), w, acc[m]);
      }
    }
}

#define BODY(XBO_, XBM_, XBN_, C) do{                                            \
  phase_old(XBO_, pv, acc);                                                      \
  __builtin_amdgcn_sched_barrier(0);                                             \
  { unsigned _xs = (unsigned)(4 * (C) + 4) * 16384u;                             \
    BLX4(XBO_[0], _xs);                                                          \
    BLX4(XBO_[1], _xs + 16384u);                                                 \
    BLX4(XBO_[2], _xs + 32768u);                                                 \
    BLX4(XBO_[3], _xs + 49152u);                                                 \
    unsigned _ps = pbase - 32768u * (unsigned)((C) + 1);                         \
    BLP4_0(npv[0], _ps); BLP4_16(npv[1], _ps); }                                 \
  __builtin_amdgcn_sched_barrier(0);                                             \
  phase_mid_new(XBM_, XBN_, pv, acc);                                            \
  asm volatile("s_waitcnt vmcnt(0)" ::: "memory");                               \
  __builtin_amdgcn_sched_barrier(0);                                             \
  pv[0] = npv[0]; pv[1] = npv[1];                                                \
}while(0)

__global__ __launch_bounds__(256, 4)
void k_conv(const unsigned int* __restrict__ Bg,     // Bg4 interleaved (see k_gemm)
            const unsigned int* __restrict__ pepk2,  // [64][1024][8] pe pairs
            float* __restrict__ out){                // [4][2048][1024] f32
  int tid  = threadIdx.x;
  int bid  = blockIdx.x;                    // 0..1023
  int bp   = bid & 7;                       // XCD pin: stream -> one XCD
  int rest = bid >> 3;                      // 0..127
  int dblk = rest & 3;
  int mt   = 31 - (rest >> 2);              // LPT: longest tiles dispatch first
  int b = bp >> 1, p = bp & 1;
  int d = dblk * 256 + tid;                 // 0..1023

  uint32x4 xrsrc = make_srsrc(Bg + (size_t)bp * 1048576, 4194304u);  // 4MB stream
  uint32x4 prsrc = make_srsrc(pepk2, 2097152u);

  unsigned voff  = (unsigned)(d * 16);      // lane's 16B within a quad row
  unsigned pvoff = (unsigned)(d * 32);      // lane's 32B pe record within a chunk

  uint32x4 B0[4], B1[4], B2[4], pv[2], npv[2];
  float acc[32];

  unsigned pbase = (2u * (unsigned)mt + 1u) * 32768u;  // pe chunk-0 byte offset
  int nch = 2 * mt + 2;

  #pragma unroll
  for (int m = 0; m < 32; ++m) acc[m] = 0.f;

  // prologue: chunk-0 window quads -8..3 (negatives OOB -> 0) + pe
  #pragma unroll
  for (int k = 0; k < 4; ++k) BLX4(B0[k], (unsigned)(k - 8) * 16384u);
  #pragma unroll
  for (int k = 0; k < 4; ++k) BLX4(B1[k], (unsigned)(k - 4) * 16384u);
  #pragma unroll
  for (int k = 0; k < 4; ++k) BLX4(B2[k], (unsigned)k * 16384u);
  BLP4_0(pv[0], pbase); BLP4_16(pv[1], pbase);
  asm volatile("s_waitcnt vmcnt(0)" ::: "memory");
  __builtin_amdgcn_sched_barrier(0);

  int c = 0;
  for (;;){
    BODY(B0, B1, B2, c); if (++c == nch) break;
    BODY(B1, B2, B0, c); if (++c == nch) break;
    BODY(B2, B0, B1, c); if (++c == nch) break;
  }

  float* oc = out + ((size_t)(b * SEQ + p) * 1024 + d) + (size_t)mt * 32 * 2048;
  #pragma unroll
  for (int m = 0; m < 32; ++m)
    __builtin_nontemporal_store(acc[m], oc + (size_t)m * 2048);
}

extern "C" void kernel_launch(void* const* d_in, const int* in_sizes, int n_in,
                              void* d_out, int out_size, void* d_ws, size_t ws_size,
                              hipStream_t stream){
  const float* x       = (const float*)d_in[0];
  const float* filters = (const float*)d_in[1];
  const float* Mi      = (const float*)d_in[2];
  const float* Mf      = (const float*)d_in[3];

  char* ws = (char*)d_ws;
  unsigned short* Xb    = (unsigned short*)(ws);                              // 16 MB
  unsigned int*   Bg    = (unsigned int*)  (ws + (size_t)16 * 1024 * 1024);   // 32 MB
  unsigned short* MbT   = (unsigned short*)(ws + (size_t)48 * 1024 * 1024);   //  2 MB
  unsigned int*   pepk2 = (unsigned int*)  (ws + (size_t)50 * 1024 * 1024);   //  2 MB
  float* out = (float*)d_out;

  hipLaunchKernelGGL(k_cvt_x, dim3(8192), dim3(256), 0, stream, x, Xb);
  hipLaunchKernelGGL(k_tr_M,  dim3(32, 32), dim3(32, 8), 0, stream, Mi, MbT);
  hipLaunchKernelGGL(k_pe,    dim3(2, 1024), dim3(256), 0, stream, filters, Mf, pepk2);
  hipLaunchKernelGGL(k_gemm,  dim3(64, 8), dim3(256), 0, stream, Xb, MbT, Bg);
  // 65536 B dynamic LDS per block: caps residency at 2 blocks/CU (160 KiB pool)
  // -> 512 resident slots serve 1024 LPT-ordered blocks with HW backfill.
  hipLaunchKernelGGL(k_conv,  dim3(1024), dim3(256), 65536, stream, Bg, pepk2, out);
}

// Round 25
// 120.164 us; speedup vs baseline: 1.2878x; 1.0645x over previous
//
#include <hip/hip_runtime.h>
#include <hip/hip_bf16.h>
#include <stdint.h>
#include <stddef.h>

#define DIM 1024
#define SEQ 2048
#define KF 24

using f32x4    = __attribute__((ext_vector_type(4))) float;
using bf16x8   = __attribute__((ext_vector_type(8))) short;
using uint32x4 = __attribute__((ext_vector_type(4))) unsigned int;

__device__ __forceinline__ unsigned short f2bf(float f){
  union { float f; unsigned int i; } v; v.f = f;
  unsigned int r = v.i + 0x7FFFu + ((v.i >> 16) & 1u);  // RNE
  return (unsigned short)(r >> 16);
}
// D = a.bf16[0]*b.bf16[0] + a.bf16[1]*b.bf16[1] + c   (V_DOT2_F32_BF16, VOP3P)
__device__ __forceinline__ float dot2bf(unsigned int a, unsigned int b, float c){
  float d;
  asm("v_dot2_f32_bf16 %0, %1, %2, %3" : "=v"(d) : "v"(a), "v"(b), "v"(c));
  return d;
}
// D = low32({a,b} >> 16): lo16 = b.hi, hi16 = a.lo
__device__ __forceinline__ unsigned abit16(unsigned a, unsigned b){
  unsigned d;
  asm("v_alignbit_b32 %0, %1, %2, 16" : "=v"(d) : "v"(a), "v"(b));
  return d;
}
__device__ __forceinline__ unsigned vext(const uint32x4 v, int i){
  return i == 0 ? v.x : i == 1 ? v.y : i == 2 ? v.z : v.w;
}
__device__ __forceinline__ void gload_lds16(const void* g, void* l){
  __builtin_amdgcn_global_load_lds(
      (const __attribute__((address_space(1))) unsigned int*)g,
      (__attribute__((address_space(3))) unsigned int*)l, 16, 0, 0);
}

// ---------------- prep: x fp32 -> bf16 ----------------
__global__ void k_cvt_x(const float* __restrict__ x, unsigned short* __restrict__ xb){
  int i = blockIdx.x * 256 + threadIdx.x;            // each thread 4 elems
  const float4* x4 = (const float4*)x;
  float4 v = x4[i];
  ushort4 o;
  o.x = f2bf(v.x); o.y = f2bf(v.y); o.z = f2bf(v.z); o.w = f2bf(v.w);
  *(ushort4*)(xb + (size_t)i * 4) = o;
}

// ---------------- prep: M_inputs transpose -> bf16 (B^T, [d][e]) ----------------
__global__ void k_tr_M(const float* __restrict__ Mi, unsigned short* __restrict__ MbT){
  __shared__ float tile[32][33];
  int e0 = blockIdx.y * 32, d0 = blockIdx.x * 32;
  int tx = threadIdx.x, ty = threadIdx.y;            // block (32,8)
  #pragma unroll
  for (int r = 0; r < 32; r += 8)
    tile[ty + r][tx] = Mi[(size_t)(e0 + ty + r) * DIM + d0 + tx];
  __syncthreads();
  #pragma unroll
  for (int r = 0; r < 32; r += 8)
    MbT[(size_t)(d0 + ty + r) * DIM + e0 + tx] = f2bf(tile[tx][ty + r]);
}

// ---------------- prep: pe packed pairs, SWAPPED, chunk-interleaved [k][d][8] -------
// pepk2[k][d][i] = u32{ lo = pe_odd, hi = pe_even } for tap pair r2 = 8k+i,
// pe_even = 2*phi[4r2], pe_odd = 2*phi[4r2+2].  Swapped so dot2 against the
// alignbit-built y-pair (lo=y_{j-1}, hi=y_j) gives pe_even*y_j + pe_odd*y_{j-1}.
__global__ void k_pe(const float* __restrict__ filters, const float* __restrict__ Mf,
                     unsigned int* __restrict__ pepk2){
  int r2 = blockIdx.x * 256 + threadIdx.x;           // 0..511 (grid.x = 2)
  int d  = blockIdx.y;                               // 0..1023
  float a0 = 0.f, a1 = 0.f;
  #pragma unroll
  for (int k = 0; k < KF; ++k){
    float mf = Mf[(size_t)k * DIM + d];              // uniform per block
    a0 += filters[(size_t)(4 * r2)     * KF + k] * mf;
    a1 += filters[(size_t)(4 * r2 + 2) * KF + k] * mf;
  }
  unsigned int lo = f2bf(2.f * a1), hi = f2bf(2.f * a0);   // SWAPPED
  pepk2[(size_t)(r2 >> 3) * 8192 + (size_t)d * 8 + (r2 & 7)] = lo | (hi << 16);
}

// ---------------- GEMM: x_proj = x @ M_inputs, epilogue writes PLAIN y8 ------------
// y8 u16 element (b,p,j,d) at index (b*2+p)*1048576 + (j>>3)*8192 + d*8 + (j&7).
// Single u16 store per value (16MB total, half the bigram write traffic).
#define BM 128
#define BN 128
#define BKK 64
__global__ void k_gemm(const unsigned short* __restrict__ A,
                       const unsigned short* __restrict__ Bt,
                       unsigned short* __restrict__ Y8){
  __shared__ unsigned short As[BM * BKK];   // 16 KB, XOR-swizzled (unit16B ^= row&7)
  __shared__ unsigned short Bs[BN * BKK];   // 16 KB
  int tid  = threadIdx.x;
  int lane = tid & 63, wave = tid >> 6;
  int wm = wave >> 1, wn = wave & 1;
  int trow0 = blockIdx.x * BM;
  int ncol0 = blockIdx.y * BN;

  f32x4 acc[4][4] = {};

  for (int kt = 0; kt < 1024 / BKK; ++kt){
    __syncthreads();
    #pragma unroll
    for (int g = 0; g < 4; ++g){
      int c  = wave * 4 + g;              // chunk 0..15, 1KB each
      int mr = c * 8 + (lane >> 3);       // tile row this lane stages
      int u  = lane & 7;                  // physical 16B unit within row
      int su = u ^ (mr & 7);              // source (logical) unit
      const unsigned short* srcA = A + (size_t)(trow0 + mr) * 1024 + kt * BKK + su * 8;
      gload_lds16(srcA, (char*)As + c * 1024);
      const unsigned short* srcB = Bt + (size_t)(ncol0 + mr) * 1024 + kt * BKK + su * 8;
      gload_lds16(srcB, (char*)Bs + c * 1024);
    }
    __syncthreads();

    bf16x8 af[4][2], bfr[4][2];
    #pragma unroll
    for (int mi = 0; mi < 4; ++mi){
      int row = wm * 64 + mi * 16 + (lane & 15);
      #pragma unroll
      for (int ks = 0; ks < 2; ++ks){
        int u = ((lane >> 4) + 4 * ks) ^ (row & 7);
        af[mi][ks] = *(const bf16x8*)((const char*)As + row * 128 + u * 16);
      }
    }
    #pragma unroll
    for (int ni = 0; ni < 4; ++ni){
      int row = wn * 64 + ni * 16 + (lane & 15);
      #pragma unroll
      for (int ks = 0; ks < 2; ++ks){
        int u = ((lane >> 4) + 4 * ks) ^ (row & 7);
        bfr[ni][ks] = *(const bf16x8*)((const char*)Bs + row * 128 + u * 16);
      }
    }
    #pragma unroll
    for (int mi = 0; mi < 4; ++mi)
      #pragma unroll
      for (int ni = 0; ni < 4; ++ni)
        #pragma unroll
        for (int ks = 0; ks < 2; ++ks)
          acc[mi][ni] = __builtin_amdgcn_mfma_f32_16x16x32_bf16(
              af[mi][ks], bfr[ni][ks], acc[mi][ni], 0, 0, 0);
  }

  #pragma unroll
  for (int mi = 0; mi < 4; ++mi)
    #pragma unroll
    for (int ni = 0; ni < 4; ++ni){
      int col = ncol0 + wn * 64 + ni * 16 + (lane & 15);
      #pragma unroll
      for (int reg = 0; reg < 4; ++reg){
        int row = trow0 + wm * 64 + mi * 16 + (lane >> 4) * 4 + reg;
        unsigned short y = f2bf(acc[mi][ni][reg]);
        int t = row & 2047, bq = row >> 11;
        int p = t & 1, j = t >> 1;
        size_t e = ((size_t)(bq * 2 + p)) * 1048576 +
                   (size_t)(j >> 3) * 8192 + (size_t)col * 8 + (j & 7);
        Y8[e] = y;
      }
    }
}

// ---------------- depthwise causal conv: plain-y8, global_load, v-only offsets -----
// out[m0+m] = sum_{r<=m0+m} pe[r]*y[m0+m-r], m in [0,32), one tile per block.
// Pair P'(j) = (lo=y_{j-1}, hi=y_j); dot2 with swapped pe == R18/R22 math.
// Per chunk c: phase_old (56 dot2, oldest pair slot) -> issue 2 x dwordx4
// (group c+1, 8KB: HALF the bigram traffic) + 2 pe dwordx4 -> phase_mid_new
// (200 dot2) -> vmcnt(0)+sched_barrier (rule 18) -> build 16 pairs into the
// vacated slot (8 alignbit; odd pairs are raw words).  Loads use
// global_load_dwordx4 with LOOP-INVARIANT "s" base + VGPR 32-bit offset: no
// loop-carried "s" operand exists, eliminating the R13/R23/R24 compile-failure
// class.  No consumed load is ever OOB (j<0 padding = zeroed P0/P1; final
// chunk's prefetches are dead), so dead-prefetch offsets are just clamped
// in-bounds (x: group &63; pe: max(,0)).
#define GLD4(dst, vo, base) do{ unsigned _vo = (vo);                             \
  asm volatile("global_load_dwordx4 %0, %1, %2"                                  \
               : "=v"(dst) : "v"(_vo), "s"(base)); }while(0)

__device__ __forceinline__ void phase_old(const unsigned* PA, const uint32x4* pv,
                                          float* acc){
  #pragma unroll
  for (int q = 0; q < 8; ++q)
    #pragma unroll
    for (int m = 0; m < 32; ++m){
      int idx = m - 2 * q + 16;
      if (idx >= 2 && idx < 16)
        acc[m] = dot2bf(vext(pv[q >> 2], q & 3), PA[idx], acc[m]);
    }
}
__device__ __forceinline__ void phase_mid_new(const unsigned* PM, const unsigned* PN,
                                              const uint32x4* pv, float* acc){
  #pragma unroll
  for (int q = 0; q < 8; ++q)
    #pragma unroll
    for (int m = 0; m < 32; ++m){
      int idx = m - 2 * q + 16;
      if (idx >= 16){
        unsigned w = (idx < 32) ? PM[idx - 16] : PN[idx - 32];
        acc[m] = dot2bf(vext(pv[q >> 2], q & 3), w, acc[m]);
      }
    }
}
// P[2i] = (lo=y_{2i-1}, hi=y_{2i}) via alignbit; P[2i+1] = w_i = (y_{2i}, y_{2i+1})
__device__ __forceinline__ void build_pairs(unsigned* P, uint32x4 r0, uint32x4 r1,
                                            unsigned& carry){
  unsigned w0 = r0.x, w1 = r0.y, w2 = r0.z, w3 = r0.w;
  unsigned w4 = r1.x, w5 = r1.y, w6 = r1.z, w7 = r1.w;
  P[0]  = abit16(w0, carry); P[1]  = w0;
  P[2]  = abit16(w1, w0);    P[3]  = w1;
  P[4]  = abit16(w2, w1);    P[5]  = w2;
  P[6]  = abit16(w3, w2);    P[7]  = w3;
  P[8]  = abit16(w4, w3);    P[9]  = w4;
  P[10] = abit16(w5, w4);    P[11] = w5;
  P[12] = abit16(w6, w5);    P[13] = w6;
  P[14] = abit16(w7, w6);    P[15] = w7;
  carry = w7;
}

#define BODY(PA_, PM_, PN_, C) do{                                               \
  phase_old(PA_, pv, acc);                                                       \
  __builtin_amdgcn_sched_barrier(0);                                             \
  { unsigned _g = (unsigned)(2 * ((C) + 1)) & 127u;   /* dead prefetch wraps */  \
    GLD4(r0, voff + _g * 16384u, xb);                                            \
    GLD4(r1, voff + _g * 16384u + 16384u, xb);                                   \
    int _pr = (int)pbase - 32768 * ((C) + 1);                                    \
    unsigned _ps = (_pr < 0) ? 0u : (unsigned)_pr;    /* dead prefetch clamps */ \
    GLD4(npv[0], pvoff + _ps, pb);                                               \
    GLD4(npv[1], pvoff + _ps + 16u, pb); }                                       \
  __builtin_amdgcn_sched_barrier(0);                                             \
  phase_mid_new(PM_, PN_, pv, acc);                                              \
  asm volatile("s_waitcnt vmcnt(0)" ::: "memory");                               \
  __builtin_amdgcn_sched_barrier(0);                                             \
  build_pairs(PA_, r0, r1, carry);                                               \
  pv[0] = npv[0]; pv[1] = npv[1];                                                \
}while(0)

__global__ __launch_bounds__(256, 4)
void k_conv(const unsigned short* __restrict__ Y8,   // plain y8 (see k_gemm)
            const unsigned int* __restrict__ pepk2,  // [64][1024][8] pe pairs
            float* __restrict__ out){                // [4][2048][1024] f32
  int tid  = threadIdx.x;
  int bid  = blockIdx.x;                    // 0..1023
  int bp   = bid & 7;                       // XCD pin: stream -> one XCD
  int rest = bid >> 3;                      // 0..127
  int dblk = rest & 3;
  int mt   = 31 - (rest >> 2);              // LPT: longest tiles dispatch first
  int b = bp >> 1, p = bp & 1;
  int d = dblk * 256 + tid;                 // 0..1023

  const unsigned short* xb = Y8 + (size_t)bp * 1048576;  // uniform, loop-invariant
  const unsigned int*   pb = pepk2;                      // uniform, loop-invariant

  unsigned voff  = (unsigned)(d * 16);      // lane's 16B (8 y) within a j-group
  unsigned pvoff = (unsigned)(d * 32);      // lane's 32B pe record within a chunk

  unsigned P0[16], P1[16], P2[16];
  uint32x4 r0, r1, pv[2], npv[2];
  float acc[32];
  unsigned carry = 0u;

  unsigned pbase = (2u * (unsigned)mt + 1u) * 32768u;  // pe chunk-0 byte offset
  int nch = 2 * mt + 2;

  #pragma unroll
  for (int m = 0; m < 32; ++m) acc[m] = 0.f;
  #pragma unroll
  for (int t = 0; t < 16; ++t){ P0[t] = 0u; P1[t] = 0u; }  // groups -2, -1 (j<0)

  // prologue: group 0 raw + pe chunk 0
  GLD4(r0, voff, xb);
  GLD4(r1, voff + 16384u, xb);
  GLD4(pv[0], pvoff + pbase, pb);
  GLD4(pv[1], pvoff + pbase + 16u, pb);
  asm volatile("s_waitcnt vmcnt(0)" ::: "memory");
  __builtin_amdgcn_sched_barrier(0);
  build_pairs(P2, r0, r1, carry);           // group 0 (y_{-1} = carry 0)

  int c = 0;
  for (;;){
    BODY(P0, P1, P2, c); if (++c == nch) break;
    BODY(P1, P2, P0, c); if (++c == nch) break;
    BODY(P2, P0, P1, c); if (++c == nch) break;
  }

  float* oc = out + ((size_t)(b * SEQ + p) * 1024 + d) + (size_t)mt * 32 * 2048;
  #pragma unroll
  for (int m = 0; m < 32; ++m)
    __builtin_nontemporal_store(acc[m], oc + (size_t)m * 2048);
}

extern "C" void kernel_launch(void* const* d_in, const int* in_sizes, int n_in,
                              void* d_out, int out_size, void* d_ws, size_t ws_size,
                              hipStream_t stream){
  const float* x       = (const float*)d_in[0];
  const float* filters = (const float*)d_in[1];
  const float* Mi      = (const float*)d_in[2];
  const float* Mf      = (const float*)d_in[3];

  char* ws = (char*)d_ws;
  unsigned short* Xb    = (unsigned short*)(ws);                              // 16 MB
  unsigned short* Y8    = (unsigned short*)(ws + (size_t)16 * 1024 * 1024);   // 16 MB
  unsigned short* MbT   = (unsigned short*)(ws + (size_t)48 * 1024 * 1024);   //  2 MB
  unsigned int*   pepk2 = (unsigned int*)  (ws + (size_t)50 * 1024 * 1024);   //  2 MB
  float* out = (float*)d_out;

  hipLaunchKernelGGL(k_cvt_x, dim3(8192), dim3(256), 0, stream, x, Xb);
  hipLaunchKernelGGL(k_tr_M,  dim3(32, 32), dim3(32, 8), 0, stream, Mi, MbT);
  hipLaunchKernelGGL(k_pe,    dim3(2, 1024), dim3(256), 0, stream, filters, Mf, pepk2);
  hipLaunchKernelGGL(k_gemm,  dim3(64, 8), dim3(256), 0, stream, Xb, MbT, Y8);
  // 65536 B dynamic LDS per block: caps residency at 2 blocks/CU (160 KiB pool)
  // -> 512 resident slots serve 1024 LPT-ordered blocks with HW backfill.
  hipLaunchKernelGGL(k_conv,  dim3(1024), dim3(256), 65536, stream, Y8, pepk2, out);
}